// Round 12
// baseline (98.174 us; speedup 1.0000x reference)
//
#include <hip/hip_runtime.h>

#define NQ    14
#define DIMQ  16384
#define NWG   64     // 64 WGs of ONE wave each
#define NTHR  64

typedef float vfloat4 __attribute__((ext_vector_type(4)));

struct Smem {
    float2 tabLo[64];    // e^{i phi} for ZZ couplers 0..5
    float2 tabHi[128];   // e^{i phi} for ZZ couplers 6..12
    float  red[48];      // final 42 sums (epilogue broadcast)
};

// ---------------------------------------------------------------------------
// Self-validating dataflow sync (proven R11): phase p stores amp + B_p
// (B alternates -4/+4, |amp| <= 1). Reader validates v*B_p > 8 and retries;
// 0xAA poison fails. Reader-of-k and writer-of-k in a phase are the same WG,
// so no WAR hazard and period-2 bias cannot alias.
// ---------------------------------------------------------------------------
__device__ __forceinline__ void ld8v(const float2* p, float rb, float2 r[4]) {
    vfloat4 a, b;
    for (;;) {
        asm volatile("global_load_dwordx4 %0, %2, off sc0 sc1\n\t"
                     "global_load_dwordx4 %1, %2, off offset:16 sc0 sc1\n\t"
                     "s_waitcnt vmcnt(0)"
                     : "=&v"(a), "=&v"(b) : "v"(p) : "memory");
        float m0 = fminf(fminf(a.x * rb, a.y * rb), fminf(a.z * rb, a.w * rb));
        float m1 = fminf(fminf(b.x * rb, b.y * rb), fminf(b.z * rb, b.w * rb));
        bool ok = fminf(m0, m1) > 8.0f;
        if (__ballot(!ok) == 0ull) break;
        __builtin_amdgcn_s_sleep(1);
    }
    r[0] = make_float2(a.x - rb, a.y - rb); r[1] = make_float2(a.z - rb, a.w - rb);
    r[2] = make_float2(b.x - rb, b.y - rb); r[3] = make_float2(b.z - rb, b.w - rb);
}
__device__ __forceinline__ void st8b(float2* p, const float2 r[4], float wb) {
    vfloat4 a, b;
    a.x = r[0].x + wb; a.y = r[0].y + wb; a.z = r[1].x + wb; a.w = r[1].y + wb;
    b.x = r[2].x + wb; b.y = r[2].y + wb; b.z = r[3].x + wb; b.w = r[3].y + wb;
    asm volatile("global_store_dwordx4 %0, %1, off sc0 sc1\n\t"
                 "global_store_dwordx4 %0, %2, off offset:16 sc0 sc1"
                 : : "v"(p), "v"(a), "v"(b) : "memory");
}
__device__ __forceinline__ void stfb(float* p, float v, float wb) {
    float e = v + wb;
    asm volatile("global_store_dword %0, %1, off sc0 sc1" : : "v"(p), "v"(e) : "memory");
}
// Epilogue: one lane gathers one WG's 48-float partial block (12 KB total per
// wave, contiguous, ONE waitcnt). Validate only elements 0..41 (42..47 pad).
// P entries are biased -4 (write-once): fresh <=> raw < -2.
__device__ __forceinline__ void ld48v(const float* p, vfloat4 v[12]) {
    for (;;) {
        asm volatile(
            "global_load_dwordx4 %0,  %12, off sc0 sc1\n\t"
            "global_load_dwordx4 %1,  %12, off offset:16 sc0 sc1\n\t"
            "global_load_dwordx4 %2,  %12, off offset:32 sc0 sc1\n\t"
            "global_load_dwordx4 %3,  %12, off offset:48 sc0 sc1\n\t"
            "global_load_dwordx4 %4,  %12, off offset:64 sc0 sc1\n\t"
            "global_load_dwordx4 %5,  %12, off offset:80 sc0 sc1\n\t"
            "global_load_dwordx4 %6,  %12, off offset:96 sc0 sc1\n\t"
            "global_load_dwordx4 %7,  %12, off offset:112 sc0 sc1\n\t"
            "global_load_dwordx4 %8,  %12, off offset:128 sc0 sc1\n\t"
            "global_load_dwordx4 %9,  %12, off offset:144 sc0 sc1\n\t"
            "global_load_dwordx4 %10, %12, off offset:160 sc0 sc1\n\t"
            "global_load_dwordx4 %11, %12, off offset:176 sc0 sc1\n\t"
            "s_waitcnt vmcnt(0)"
            : "=&v"(v[0]), "=&v"(v[1]), "=&v"(v[2]), "=&v"(v[3]),
              "=&v"(v[4]), "=&v"(v[5]), "=&v"(v[6]), "=&v"(v[7]),
              "=&v"(v[8]), "=&v"(v[9]), "=&v"(v[10]), "=&v"(v[11])
            : "v"(p) : "memory");
        float mx = -1e30f;
#pragma unroll
        for (int k = 0; k < 10; ++k)
            mx = fmaxf(mx, fmaxf(fmaxf(v[k].x, v[k].y), fmaxf(v[k].z, v[k].w)));
        mx = fmaxf(mx, fmaxf(v[10].x, v[10].y));
        bool ok = mx < -2.0f;
        if (__ballot(!ok) == 0ull) break;
        __builtin_amdgcn_s_sleep(1);
    }
}

// ---------------- gate math ------------------------------------------------
__device__ __forceinline__ float2 cmulf(float2 a, float2 b) {
    return make_float2(a.x * b.x - a.y * b.y, a.x * b.y + a.y * b.x);
}
__device__ __forceinline__ void bfly(float2& p0, float2& p1, float c, float s) {
    float2 n0 = make_float2(c * p0.x + s * p1.y, c * p0.y - s * p1.x);
    float2 n1 = make_float2(c * p1.x + s * p0.y, c * p1.y - s * p0.x);
    p0 = n0; p1 = n1;
}
__device__ __forceinline__ void bfly_shfl(float2& p, int mask, float c, float s) {
    float qx = __shfl_xor(p.x, mask);
    float qy = __shfl_xor(p.y, mask);
    p = make_float2(c * p.x + s * qy, c * p.y - s * qx);
}
__device__ __forceinline__ void zz_apply(const Smem& sm, float2& a, int k) {
    int d = (k ^ (k >> 1)) & 0x1FFF;
    float2 rot = cmulf(sm.tabLo[d & 63], sm.tabHi[d >> 6]);
    a = cmulf(a, rot);
}
// RX on reg qubits 0 (pairs 01,23) and 1 (pairs 02,13)
__device__ __forceinline__ void rx_reg01(float2 r[4], const float* c, const float* s) {
    bfly(r[0], r[1], c[0], s[0]); bfly(r[2], r[3], c[0], s[0]);
    bfly(r[0], r[2], c[1], s[1]); bfly(r[1], r[3], c[1], s[1]);
}

// ---------------- reductions (1 wave, no LDS) ------------------------------
__device__ __forceinline__ void wave_store_triple(float cr, float ci, float z,
                                                  float* P, int wg, int i) {
#pragma unroll
    for (int off = 32; off; off >>= 1) {
        cr += __shfl_down(cr, off);
        ci += __shfl_down(ci, off);
        z  += __shfl_down(z, off);
    }
    if (threadIdx.x == 0) {
        stfb(&P[wg * 48 + 3 * i + 0], cr, -4.0f);
        stfb(&P[wg * 48 + 3 * i + 1], ci, -4.0f);
        stfb(&P[wg * 48 + 3 * i + 2], z,  -4.0f);
    }
}
// qubit at LANE bit b; triple index i
__device__ __forceinline__ void reduce_lane_qubit(const float2 r[4], int b,
                                                  float* P, int wg, int i, int t) {
    const int bit = (t >> b) & 1;
    const float sel = bit ? 0.0f : 1.0f;
    float cr = 0.f, ci = 0.f, z = 0.f;
#pragma unroll
    for (int j = 0; j < 4; ++j) {
        const float px = __shfl_xor(r[j].x, 1 << b);
        const float py = __shfl_xor(r[j].y, 1 << b);
        const float n  = r[j].x * r[j].x + r[j].y * r[j].y;
        cr += sel * (r[j].x * px + r[j].y * py);
        ci += sel * (r[j].x * py - r[j].y * px);
        z  += bit ? -n : n;
    }
    wave_store_triple(cr, ci, z, P, wg, i);
}

// ---- Phase A: k = (wg<<8)|(t<<2)|j. Local {0..7}; applies RX{2..7}
// (lane bit b = qubit 2+b). Leftover entering: RX_s{2..7}.
template <bool FIRST>
__device__ void phaseA(const Smem& sm, float2* psi, int base,
                       const float* c, const float* s, float rb, float wb) {
    float2 r[4];
    if (FIRST) {
#pragma unroll
        for (int j = 0; j < 4; ++j) r[j] = make_float2(0.0078125f, 0.0f);
    } else {
        ld8v(&psi[base], rb, r);
#pragma unroll
        for (int b = 0; b < 6; ++b)
#pragma unroll
            for (int j = 0; j < 4; ++j) bfly_shfl(r[j], 1 << b, c[2 + b], s[2 + b]);
    }
#pragma unroll
    for (int j = 0; j < 4; ++j) zz_apply(sm, r[j], base | j);
#pragma unroll
    for (int b = 0; b < 6; ++b)
#pragma unroll
        for (int j = 0; j < 4; ++j) bfly_shfl(r[j], 1 << b, c[2 + b], s[2 + b]);
    st8b(&psi[base], r, wb);
}

// ---- Phase B: k = (t<<8)|(wg<<2)|j. Local {0,1,8..13}; applies RX{0,1}
// (regs) + RX{8..13} (lane bit b = qubit 8+b). Leftover: RX_s{0,1,8..13}.
// REDUCE (phase 10): expectations for {0,1,8..13} — remaining RX_10{2..7}
// acts on other qubits and commutes with these measurements.
template <bool REDUCE>
__device__ void phaseB(const Smem& sm, float2* psi, float* P, int base,
                       int wg, int t, const float* c, const float* s,
                       float rb, float wb) {
    float2 r[4];
    ld8v(&psi[base], rb, r);
    rx_reg01(r, c, s);
#pragma unroll
    for (int b = 0; b < 6; ++b)
#pragma unroll
        for (int j = 0; j < 4; ++j) bfly_shfl(r[j], 1 << b, c[8 + b], s[8 + b]);
#pragma unroll
    for (int j = 0; j < 4; ++j) zz_apply(sm, r[j], base | j);
    rx_reg01(r, c, s);
#pragma unroll
    for (int b = 0; b < 6; ++b)
#pragma unroll
        for (int j = 0; j < 4; ++j) bfly_shfl(r[j], 1 << b, c[8 + b], s[8 + b]);
    st8b(&psi[base], r, wb);

    if (REDUCE) {
        // q0 (reg, pairs 01,23) -> i=13
        {
            float cr = r[0].x*r[1].x + r[0].y*r[1].y + r[2].x*r[3].x + r[2].y*r[3].y;
            float ci = r[0].x*r[1].y - r[0].y*r[1].x + r[2].x*r[3].y - r[2].y*r[3].x;
            float z  = (r[0].x*r[0].x + r[0].y*r[0].y + r[2].x*r[2].x + r[2].y*r[2].y)
                     - (r[1].x*r[1].x + r[1].y*r[1].y + r[3].x*r[3].x + r[3].y*r[3].y);
            wave_store_triple(cr, ci, z, P, wg, 13);
        }
        // q1 (reg, pairs 02,13) -> i=12
        {
            float cr = r[0].x*r[2].x + r[0].y*r[2].y + r[1].x*r[3].x + r[1].y*r[3].y;
            float ci = r[0].x*r[2].y - r[0].y*r[2].x + r[1].x*r[3].y - r[1].y*r[3].x;
            float z  = (r[0].x*r[0].x + r[0].y*r[0].y + r[1].x*r[1].x + r[1].y*r[1].y)
                     - (r[2].x*r[2].x + r[2].y*r[2].y + r[3].x*r[3].x + r[3].y*r[3].y);
            wave_store_triple(cr, ci, z, P, wg, 12);
        }
        // q8+b (lane bit b) -> i = 5-b
#pragma unroll
        for (int b = 0; b < 6; ++b) reduce_lane_qubit(r, b, P, wg, 5 - b, t);
    }
}

extern "C" __global__ void __launch_bounds__(NTHR)
qr_all(const float* __restrict__ x, const float* __restrict__ J,
       const float* __restrict__ g, float* __restrict__ out,
       float2* __restrict__ psi, float* __restrict__ P) {
    __shared__ Smem sm;
    const int wg = blockIdx.x;
    const int t  = threadIdx.x;
    const float dt = 0.1f;   // EVO_TIME / N_TROTTER

    // ZZ tables (64 threads: 64 + 2x64 entries)
    {
        float phi = 0.f;
        for (int i = 0; i < 6; ++i) {
            const float h = 0.5f * J[i] * dt;
            phi += ((t >> i) & 1) ? h : -h;
        }
        float sn, cs; __sincosf(phi, &sn, &cs);
        sm.tabLo[t] = make_float2(cs, sn);
    }
#pragma unroll
    for (int rep = 0; rep < 2; ++rep) {
        const int v = t + (rep << 6);
        float phi = 0.f;
        for (int i = 0; i < 7; ++i) {
            const float h = 0.5f * J[6 + i] * dt;
            phi += ((v >> i) & 1) ? h : -h;
        }
        float sn, cs; __sincosf(phi, &sn, &cs);
        sm.tabHi[v] = make_float2(cs, sn);
    }
    float cc[NQ], ss[NQ];
#pragma unroll
    for (int i = 0; i < NQ; ++i) __sincosf(0.5f * g[i] * dt, &ss[i], &cc[i]);
    __syncthreads();

    const int aBase = (wg << 8) | (t << 2);   // layout A: wg=q8..13, t=q2..7
    const int bBase = (t << 8) | (wg << 2);   // layout B: t=q8..13, wg=q2..7

    // Phase 1 (A, p=1, wb=-4): init + ZZ_1 + RX_1{2..7}
    phaseA<true>(sm, psi, aBase, cc, ss, 0.f, -4.f);

    // Overlap: precompute epilogue sincos (7 tasks/thread) while phase-1
    // stores of other WGs land.
    float esn[7], ecs[7];
#pragma unroll
    for (int k = 0; k < 7; ++k) {
        const int task = (wg << 6) | t | (k << 12);
        const int b = task / NQ;
        const int i = task - b * NQ;
        __sincosf(x[b * NQ + 13 - i], &esn[k], &ecs[k]);
    }

    // Phases 2..10: even = B (leftover RX{0,1,8..13}, ZZ, RX{0,1,8..13}),
    // odd = A (leftover RX{2..7}, ZZ, RX{2..7}). Phase p writes bias
    // (p odd ? -4 : +4); reads previous phase's bias.
#pragma unroll 1
    for (int p = 2; p <= 10; ++p) {
        const float wb = (p & 1) ? -4.f : 4.f;
        const float rb = -wb;
        if (p & 1) {
            phaseA<false>(sm, psi, aBase, cc, ss, rb, wb);
        } else if (p == 10) {
            phaseB<true >(sm, psi, P, bBase, wg, t, cc, ss, rb, wb);
        } else {
            phaseB<false>(sm, psi, P, bBase, wg, t, cc, ss, rb, wb);
        }
    }

    // Phase 11 (A-type): leftover RX_10{2..7} + reduce q2..7 (i = 11-b).
    {
        float2 r[4];
        ld8v(&psi[aBase], 4.0f, r);   // phase 10 wrote bias +4
#pragma unroll
        for (int b = 0; b < 6; ++b)
#pragma unroll
            for (int j = 0; j < 4; ++j) bfly_shfl(r[j], 1 << b, cc[2 + b], ss[2 + b]);
#pragma unroll
        for (int b = 0; b < 6; ++b) reduce_lane_qubit(r, b, P, wg, 11 - b, t);
    }

    // Epilogue: lane t gathers WG t's 48-float partial block (contiguous,
    // validated, one waitcnt), 42 wave-reduces -> LDS -> outputs.
    vfloat4 v[12];
    ld48v(&P[t * 48], v);
#pragma unroll
    for (int e = 0; e < 42; ++e) {
        float sv = v[e >> 2][e & 3] + 4.0f;
#pragma unroll
        for (int off = 32; off; off >>= 1) sv += __shfl_down(sv, off);
        if (t == 0) sm.red[e] = sv;
    }
    __syncthreads();
#pragma unroll
    for (int k = 0; k < 7; ++k) {
        const int task = (wg << 6) | t | (k << 12);
        const int b = task / NQ;
        const int i = task - b * NQ;
        const float cr = sm.red[3 * i + 0];
        const float ci = sm.red[3 * i + 1];
        const float zz = sm.red[3 * i + 2];
        float* o = out + b * (3 * NQ) + 3 * i;
        o[0] = 2.0f * (ecs[k] * cr - esn[k] * ci);
        o[1] = 2.0f * (esn[k] * cr + ecs[k] * ci);
        o[2] = zz;
    }
}

extern "C" void kernel_launch(void* const* d_in, const int* in_sizes, int n_in,
                              void* d_out, int out_size, void* d_ws, size_t ws_size,
                              hipStream_t stream) {
    const float* x = (const float*)d_in[0];
    const float* J = (const float*)d_in[1];
    const float* g = (const float*)d_in[2];
    float* out = (float*)d_out;
    char* ws   = (char*)d_ws;
    float2* psi = (float2*)ws;                             // 128 KiB
    float*  P   = (float*)(ws + DIMQ * sizeof(float2));    // 64*48 floats, 12 KiB
    (void)in_sizes; (void)n_in; (void)out_size; (void)ws_size;

    // Single dispatch; no memset — 0xAA poison fails every bias validation,
    // so psi and P reads self-synchronize.
    hipLaunchKernelGGL(qr_all, dim3(NWG), dim3(NTHR), 0, stream,
                       x, J, g, out, psi, P);
}

// Round 15
// 92.783 us; speedup vs baseline: 1.0581x; 1.0581x over previous
//
#include <hip/hip_runtime.h>

#define NQ     14
#define DIMQ   16384
#define NWG    16
#define NTHR   256

typedef float vfloat4 __attribute__((ext_vector_type(4)));

struct Smem {
    float2 slab0[1024];  // staging slab, even stages
    float2 slab1[1024];  // staging slab, odd stages
    float2 tabLo[64];    // e^{i phi} for ZZ couplers 0..5
    float2 tabHi[128];   // e^{i phi} for ZZ couplers 6..12
    float  red[48];      // this WG's partial sums of the 42 constants
};

// ---------------------------------------------------------------------------
// Self-validating dataflow sync (proven R11): phase p stores amp + B_p
// (B alternates -4/+4, |amp| <= 1). Reader validates v*B_p > 8 and retries;
// 0xAA poison fails both. Reader-of-k = writer-of-k within a phase, so the
// next overwrite of k happens only after k's current value was consumed.
// INVARIANT (R14 post-mortem): every asm load keeps its s_waitcnt in the SAME
// asm block — split issue/wait lets the register allocator touch in-flight
// destination registers (spill/move) -> corruption -> validation livelock.
// ---------------------------------------------------------------------------
__device__ __forceinline__ void ld8v(const float2* p, float rb, float2 r[4]) {
    vfloat4 a, b;
    for (;;) {
        asm volatile("global_load_dwordx4 %0, %2, off sc0 sc1\n\t"
                     "global_load_dwordx4 %1, %2, off offset:16 sc0 sc1\n\t"
                     "s_waitcnt vmcnt(0)"
                     : "=&v"(a), "=&v"(b) : "v"(p) : "memory");
        float m0 = fminf(fminf(a.x * rb, a.y * rb), fminf(a.z * rb, a.w * rb));
        float m1 = fminf(fminf(b.x * rb, b.y * rb), fminf(b.z * rb, b.w * rb));
        bool ok = fminf(m0, m1) > 8.0f;
        if (__ballot(!ok) == 0ull) break;
        __builtin_amdgcn_s_sleep(1);
    }
    r[0] = make_float2(a.x - rb, a.y - rb); r[1] = make_float2(a.z - rb, a.w - rb);
    r[2] = make_float2(b.x - rb, b.y - rb); r[3] = make_float2(b.z - rb, b.w - rb);
}
__device__ __forceinline__ float2 d2f2(double d) { union { double d; float2 f; } u; u.d = d; return u.f; }
__device__ __forceinline__ double f22d(float2 f) { union { double d; float2 f; } u; u.f = f; return u.d; }
__device__ __forceinline__ void st2b(float2* p, float2 v, float wb) {
    float2 e = make_float2(v.x + wb, v.y + wb);
    asm volatile("global_store_dwordx2 %0, %1, off sc0 sc1"
                 : : "v"(p), "v"(f22d(e)) : "memory");
}
__device__ __forceinline__ void st8b(float2* p, const float2 r[4], float wb) {
    vfloat4 a, b;
    a.x = r[0].x + wb; a.y = r[0].y + wb; a.z = r[1].x + wb; a.w = r[1].y + wb;
    b.x = r[2].x + wb; b.y = r[2].y + wb; b.z = r[3].x + wb; b.w = r[3].y + wb;
    asm volatile("global_store_dwordx4 %0, %1, off sc0 sc1\n\t"
                 "global_store_dwordx4 %0, %2, off offset:16 sc0 sc1"
                 : : "v"(p), "v"(a), "v"(b) : "memory");
}
__device__ __forceinline__ void stfb(float* p, float v, float wb) {
    float e = v + wb;
    asm volatile("global_store_dword %0, %1, off sc0 sc1" : : "v"(p), "v"(e) : "memory");
}
__device__ __forceinline__ void ld3v(const float* p, float rb, bool use2,
                                     float& r0, float& r1, float& r2) {
    for (;;) {
        asm volatile("global_load_dword %0, %3, off sc0 sc1\n\t"
                     "global_load_dword %1, %3, off offset:1024 sc0 sc1\n\t"
                     "global_load_dword %2, %3, off offset:2048 sc0 sc1\n\t"
                     "s_waitcnt vmcnt(0)"
                     : "=&v"(r0), "=&v"(r1), "=&v"(r2) : "v"(p) : "memory");
        float m = fminf(r0 * rb, r1 * rb);
        if (use2) m = fminf(m, r2 * rb);
        bool ok = m > 8.0f;
        if (__ballot(!ok) == 0ull) break;
        __builtin_amdgcn_s_sleep(1);
    }
    r0 -= rb; r1 -= rb; r2 -= rb;
}

// ---------------- gate math ------------------------------------------------
__device__ __forceinline__ float2 cmulf(float2 a, float2 b) {
    return make_float2(a.x * b.x - a.y * b.y, a.x * b.y + a.y * b.x);
}
__device__ __forceinline__ void bfly(float2& p0, float2& p1, float c, float s) {
    float2 n0 = make_float2(c * p0.x + s * p1.y, c * p0.y - s * p1.x);
    float2 n1 = make_float2(c * p1.x + s * p0.y, c * p1.y - s * p0.x);
    p0 = n0; p1 = n1;
}
__device__ __forceinline__ void bfly_shfl(float2& p, int mask, float c, float s) {
    float qx = __shfl_xor(p.x, mask);
    float qy = __shfl_xor(p.y, mask);
    p = make_float2(c * p.x + s * qy, c * p.y - s * qx);
}
__device__ __forceinline__ void zz_apply(const Smem& sm, float2& a, int k) {
    int d = (k ^ (k >> 1)) & 0x1FFF;
    float2 rot = cmulf(sm.tabLo[d & 63], sm.tabHi[d >> 6]);
    a = cmulf(a, rot);
}
// One sync per stage: the leading sync is removable because stages alternate
// slab0/slab1 in strict parity kernel-wide, so any same-slab reuse has an
// intervening other-slab stage sync + per-thread program order between the
// old reads and the new writes (verified transition-by-transition).
__device__ __forceinline__ void stage_12(float2* slab, float2 r[4], int t) {
#pragma unroll
    for (int j = 0; j < 4; ++j) slab[(t << 2) | j] = r[j];
    __syncthreads();
#pragma unroll
    for (int j = 0; j < 4; ++j) r[j] = slab[t | (j << 8)];
}
__device__ __forceinline__ void stage_21(float2* slab, float2 r[4], int t) {
#pragma unroll
    for (int j = 0; j < 4; ++j) slab[t | (j << 8)] = r[j];
    __syncthreads();
#pragma unroll
    for (int j = 0; j < 4; ++j) r[j] = slab[(t << 2) | j];
}
// Reduce triple i over slab; qubit at slab bit sb.
__device__ __forceinline__ void reduce_qubit(const float2* slab, float* red,
                                             int sb, int i, int t) {
    float cr = 0.f, ci = 0.f, z = 0.f;
#pragma unroll
    for (int j = 0; j < 4; ++j) {
        const int m = (t << 2) | j;
        const float2 a = slab[m];
        const float n = a.x * a.x + a.y * a.y;
        if ((m >> sb) & 1) {
            z -= n;
        } else {
            z += n;
            const float2 b = slab[m ^ (1 << sb)];
            cr += a.x * b.x + a.y * b.y;
            ci += a.x * b.y - a.y * b.x;
        }
    }
#pragma unroll
    for (int off = 32; off; off >>= 1) {
        cr += __shfl_down(cr, off);
        ci += __shfl_down(ci, off);
        z  += __shfl_down(z, off);
    }
    if ((t & 63) == 0) {
        atomicAdd(&red[3 * i + 0], cr);
        atomicAdd(&red[3 * i + 1], ci);
        atomicAdd(&red[3 * i + 2], z);
    }
}

// ---- Layout A: k = (w<<10)|m. WG w = qubits 10..13; local 0..9.
template <bool FIRST>
__device__ void phaseA(Smem& sm, float2* slab, float2* psi, int w, int t,
                       const float* c, const float* s, float rb, float wb) {
    float2 r[4];
    if (FIRST) {
#pragma unroll
        for (int j = 0; j < 4; ++j) r[j] = make_float2(0.0078125f, 0.0f);
    } else {
        ld8v(&psi[(w << 10) | (t << 2)], rb, r);
#pragma unroll
        for (int b = 2; b < 6; ++b) {   // leftover RX_s{4..7}
#pragma unroll
            for (int j = 0; j < 4; ++j) bfly_shfl(r[j], 1 << b, c[2 + b], s[2 + b]);
        }
    }
#pragma unroll
    for (int j = 0; j < 4; ++j) zz_apply(sm, r[j], (w << 10) | (t << 2) | j);
    bfly(r[0], r[1], c[0], s[0]); bfly(r[2], r[3], c[0], s[0]);
    bfly(r[0], r[2], c[1], s[1]); bfly(r[1], r[3], c[1], s[1]);
#pragma unroll
    for (int b = 0; b < 6; ++b) {
#pragma unroll
        for (int j = 0; j < 4; ++j) bfly_shfl(r[j], 1 << b, c[2 + b], s[2 + b]);
    }
    stage_12(slab, r, t);   // mapping2: regs = q8,q9
    bfly(r[0], r[1], c[8], s[8]); bfly(r[2], r[3], c[8], s[8]);
    bfly(r[0], r[2], c[9], s[9]); bfly(r[1], r[3], c[9], s[9]);
#pragma unroll
    for (int j = 0; j < 4; ++j) st2b(&psi[(w << 10) | t | (j << 8)], r[j], wb);
}

// ---- Layout B': k = (hi6<<8)|(w<<4)|lo4. WG w = qubits 4..7;
// local {0..3,8..13}; 32 B contiguous per thread.
// RX_s{10..13}, ZZ_{s+1}, RX_{s+1}{0..3,8..13}. Leftover: RX_{s+1}{4..7}.
template <bool KEEPSLAB>
__device__ void phaseB(Smem& sm, float2* s12, float2* s21, float2* psi,
                       int w, int t, const float* c, const float* s,
                       float rb, float wb) {
    float2 r[4];
    const int kbase = ((t >> 2) << 8) | (w << 4) | ((t & 3) << 2);
    ld8v(&psi[kbase], rb, r);
#pragma unroll
    for (int j = 0; j < 4; ++j) bfly_shfl(r[j], 16, c[10], s[10]);
#pragma unroll
    for (int j = 0; j < 4; ++j) bfly_shfl(r[j], 32, c[11], s[11]);
    stage_12(s12, r, t);   // mapping2: regs = q12,q13
    bfly(r[0], r[1], c[12], s[12]); bfly(r[2], r[3], c[12], s[12]);
    bfly(r[0], r[2], c[13], s[13]); bfly(r[1], r[3], c[13], s[13]);
#pragma unroll
    for (int j = 0; j < 4; ++j) {
        const int m = t | (j << 8);
        zz_apply(sm, r[j], ((m >> 4) << 8) | (w << 4) | (m & 15));
    }
    bfly(r[0], r[1], c[12], s[12]); bfly(r[2], r[3], c[12], s[12]);
    bfly(r[0], r[2], c[13], s[13]); bfly(r[1], r[3], c[13], s[13]);
#pragma unroll
    for (int b = 0; b < 4; ++b) {
#pragma unroll
        for (int j = 0; j < 4; ++j) bfly_shfl(r[j], 1 << b, c[b], s[b]);
    }
#pragma unroll
    for (int j = 0; j < 4; ++j) bfly_shfl(r[j], 16, c[8], s[8]);
#pragma unroll
    for (int j = 0; j < 4; ++j) bfly_shfl(r[j], 32, c[9], s[9]);
    stage_21(s21, r, t);   // back to mapping1
#pragma unroll
    for (int j = 0; j < 4; ++j) bfly_shfl(r[j], 16, c[10], s[10]);
#pragma unroll
    for (int j = 0; j < 4; ++j) bfly_shfl(r[j], 32, c[11], s[11]);
    st8b(&psi[kbase], r, wb);
    if (KEEPSLAB) {
        // s21[(t<<2)|j] last read by this same thread in stage_21 — safe;
        // covers all 1024 entries with final (true) amps across t,j.
#pragma unroll
        for (int j = 0; j < 4; ++j) s21[(t << 2) | j] = r[j];
    }
}

extern "C" __global__ void __launch_bounds__(NTHR)
qr_all(const float* __restrict__ x, const float* __restrict__ J,
       const float* __restrict__ g, float* __restrict__ out,
       float2* __restrict__ psi, float* __restrict__ P) {
    __shared__ Smem sm;
    const int w = blockIdx.x;
    const int t = threadIdx.x;
    const float dt = 0.1f;   // EVO_TIME / N_TROTTER

    if (t < 64) {
        float phi = 0.0f;
        for (int i = 0; i < 6; ++i) {
            const float h = 0.5f * J[i] * dt;
            phi += ((t >> i) & 1) ? h : -h;
        }
        float sn, cs; __sincosf(phi, &sn, &cs);
        sm.tabLo[t] = make_float2(cs, sn);
    } else if (t < 192) {
        const int v = t - 64;
        float phi = 0.0f;
        for (int i = 0; i < 7; ++i) {
            const float h = 0.5f * J[6 + i] * dt;
            phi += ((v >> i) & 1) ? h : -h;
        }
        float sn, cs; __sincosf(phi, &sn, &cs);
        sm.tabHi[v] = make_float2(cs, sn);
    }
    if (t < 48) sm.red[t] = 0.0f;
    float cc[NQ], ss[NQ];
#pragma unroll
    for (int i = 0; i < NQ; ++i) __sincosf(0.5f * g[i] * dt, &ss[i], &cc[i]);
    __syncthreads();

    // Phase 1 (p=1, wb=-4, slab0): init + ZZ_1 + RX_1{0..9}
    phaseA<true>(sm, sm.slab0, psi, w, t, cc, ss, 0.0f, -4.0f);

    // Epilogue sincos precompute (7 tasks/thread) — covers phase-1 landing.
    float esn[7], ecs[7];
#pragma unroll
    for (int k = 0; k < 7; ++k) {
        const int task = w * NTHR + t + (k << 12);
        const int b = task / NQ;
        const int i = task - b * NQ;
        __sincosf(x[b * NQ + 13 - i], &esn[k], &ecs[k]);
    }

    // Phases 2..10: B' on odd sstep (p=sstep+1 even), A on even sstep.
    // Slab parity: A p -> (sstep>>1)&1; B s21 -> ((sstep-1)>>1)&1, s12 other.
    // (LDS pointer arrays in locals don't lower on hipcc — use ternaries.)
#pragma unroll 1
    for (int sstep = 1; sstep <= 9; ++sstep) {
        const float wb = ((sstep + 1) & 1) ? -4.0f : 4.0f;
        const float rb = -wb;
        if (sstep & 1) {
            const int i21 = ((sstep - 1) >> 1) & 1;
            float2* s21 = i21 ? sm.slab1 : sm.slab0;
            float2* s12 = i21 ? sm.slab0 : sm.slab1;
            if (sstep == 9) {
                phaseB<true>(sm, s12, s21, psi, w, t, cc, ss, rb, wb);
                // Reductions for q NOT in {4..7} (leftover RX{4..7} commutes).
                // Slab bits: q0..3 -> 0..3, q8..13 -> 4..9. Data in s21=slab0.
                __syncthreads();
#pragma unroll
                for (int q = 0; q <= 3; ++q) reduce_qubit(sm.slab0, sm.red, q, 13 - q, t);
#pragma unroll
                for (int q = 8; q <= 13; ++q) reduce_qubit(sm.slab0, sm.red, q - 4, 13 - q, t);
            } else {
                phaseB<false>(sm, s12, s21, psi, w, t, cc, ss, rb, wb);
            }
        } else {
            float2* slab = ((sstep >> 1) & 1) ? sm.slab1 : sm.slab0;
            phaseA<false>(sm, slab, psi, w, t, cc, ss, rb, wb);
        }
    }

    // Phase 11 (reads p10's +4 bias, atomic ld8v — no split prefetch):
    // leftover RX_10{4..7}, reductions q4..7 (slab1), transposed partials.
    {
        float2 r[4];
        ld8v(&psi[(w << 10) | (t << 2)], 4.0f, r);
#pragma unroll
        for (int b = 2; b < 6; ++b) {
#pragma unroll
            for (int j = 0; j < 4; ++j) bfly_shfl(r[j], 1 << b, cc[2 + b], ss[2 + b]);
        }
        // stage into slab1 (parity: p10's s21 was slab0; last slab1 use was
        // p10's s12 read, separated by p10's stage_21 sync + reduction sync)
#pragma unroll
        for (int j = 0; j < 4; ++j) sm.slab1[(t << 2) | j] = r[j];
        __syncthreads();
#pragma unroll
        for (int q = 4; q <= 7; ++q) reduce_qubit(sm.slab1, sm.red, q, 13 - q, t);
        __syncthreads();
        if (t < 42) stfb(&P[t * NWG + w], sm.red[t], -4.0f);  // transposed
    }

    // Epilogue: validated gather of 768 partial slots (rows 42..47 pad,
    // masked) -> slab0 as float sumbuf -> 42 sums -> outputs.
    float* sumbuf = (float*)sm.slab0;
    {
        float r0, r1, r2;
        ld3v(&P[t], -4.0f, t < 160, r0, r1, r2);
        sumbuf[t] = r0; sumbuf[t + 256] = r1; sumbuf[t + 512] = r2;
    }
    __syncthreads();
    float cv = 0.0f;
    if (t < 42) {
#pragma unroll
        for (int k = 0; k < NWG; ++k) cv += sumbuf[t * NWG + k];
    }
    __syncthreads();
    if (t < 42) sm.red[t] = cv;
    __syncthreads();

#pragma unroll
    for (int k = 0; k < 7; ++k) {
        const int task = w * NTHR + t + (k << 12);
        const int b = task / NQ;
        const int i = task - b * NQ;
        const float cr = sm.red[3 * i + 0];
        const float ci = sm.red[3 * i + 1];
        const float zz = sm.red[3 * i + 2];
        float* o = out + b * (3 * NQ) + 3 * i;
        o[0] = 2.0f * (ecs[k] * cr - esn[k] * ci);
        o[1] = 2.0f * (esn[k] * cr + ecs[k] * ci);
        o[2] = zz;
    }
}

extern "C" void kernel_launch(void* const* d_in, const int* in_sizes, int n_in,
                              void* d_out, int out_size, void* d_ws, size_t ws_size,
                              hipStream_t stream) {
    const float* x = (const float*)d_in[0];
    const float* J = (const float*)d_in[1];
    const float* g = (const float*)d_in[2];
    float* out = (float*)d_out;
    char* ws   = (char*)d_ws;
    float2* psi = (float2*)ws;                                  // 128 KiB
    float*  P   = (float*)(ws + DIMQ * sizeof(float2));         // 768 floats
    (void)in_sizes; (void)n_in; (void)out_size; (void)ws_size;

    // Single dispatch; no memset — 0xAA poison fails every bias validation,
    // so psi and P reads self-synchronize.
    hipLaunchKernelGGL(qr_all, dim3(NWG), dim3(NTHR), 0, stream,
                       x, J, g, out, psi, P);
}